// Round 11
// baseline (138.924 us; speedup 1.0000x reference)
//
#include <hip/hip_runtime.h>
#include <hip/hip_bf16.h>
#include <stdint.h>

using bf16   = __bf16;
using bf16x8 = __attribute__((ext_vector_type(8))) __bf16;
using f32x2  = __attribute__((ext_vector_type(2))) float;
using f32x4  = __attribute__((ext_vector_type(4))) float;

#define NN  2048   // nodes
#define DD  16     // embedding dim
#define BB  64     // batch
#define CC  64     // channels (in == out)
#define BCC 4096   // BB*CC

__device__ inline float4 f4max(float4 a, float4 b) {
  return make_float4(fmaxf(a.x,b.x), fmaxf(a.y,b.y), fmaxf(a.z,b.z), fmaxf(a.w,b.w));
}
__device__ inline float4 f4add(float4 a, float4 b) {
  return make_float4(a.x+b.x, a.y+b.y, a.z+b.z, a.w+b.w);
}

// ---------------- K1 fused prep: softmax | build_xrt | prep_wpt ------------
// blocks 0..511: softmax (4 nodes each); 512..2559: xrt tiles; 2560..2607: wpt
__global__ __launch_bounds__(256) void k_prep_fused(const float* __restrict__ E,
                                                    bf16* __restrict__ A,
                                                    const float* __restrict__ x,
                                                    bf16* __restrict__ XrT,
                                                    const float* __restrict__ Wp,
                                                    bf16* __restrict__ WpT) {
  __shared__ alignas(16) char smem[64 * 68 * 2];  // 8.7 KB union
  const int blk = blockIdx.x;
  const int t = threadIdx.x;

  if (blk < 512) {
    // ---- softmax: A[n] = softmax(relu(E E^T))[n], 4 nodes/block ----
    float4* red = (float4*)smem;
    const int n0 = blk * 4;
    float en[4][DD];
#pragma unroll
    for (int g = 0; g < 4; ++g)
#pragma unroll
      for (int d = 0; d < DD; ++d) en[g][d] = E[(size_t)(n0 + g) * DD + d];

    float4 r[8];
    float4 mx = make_float4(0.f, 0.f, 0.f, 0.f);
#pragma unroll
    for (int j = 0; j < 8; ++j) {
      const int m = t + 256 * j;
      const float4* ep = (const float4*)(E + (size_t)m * DD);
      float4 p0 = ep[0], p1 = ep[1], p2 = ep[2], p3 = ep[3];
      float s[4];
#pragma unroll
      for (int g = 0; g < 4; ++g) {
        s[g] = p0.x*en[g][0] + p0.y*en[g][1] + p0.z*en[g][2] + p0.w*en[g][3]
             + p1.x*en[g][4] + p1.y*en[g][5] + p1.z*en[g][6] + p1.w*en[g][7]
             + p2.x*en[g][8] + p2.y*en[g][9] + p2.z*en[g][10] + p2.w*en[g][11]
             + p3.x*en[g][12]+ p3.y*en[g][13]+ p3.z*en[g][14]+ p3.w*en[g][15];
        s[g] = fmaxf(s[g], 0.0f);
      }
      r[j] = make_float4(s[0], s[1], s[2], s[3]);
      mx = f4max(mx, r[j]);
    }
    red[t] = mx;
    __syncthreads();
    for (int off = 128; off > 0; off >>= 1) {
      if (t < off) red[t] = f4max(red[t], red[t + off]);
      __syncthreads();
    }
    mx = red[0];
    __syncthreads();
    float4 ex[8];
    float4 sum = make_float4(0.f, 0.f, 0.f, 0.f);
#pragma unroll
    for (int j = 0; j < 8; ++j) {
      ex[j] = make_float4(__expf(r[j].x - mx.x), __expf(r[j].y - mx.y),
                          __expf(r[j].z - mx.z), __expf(r[j].w - mx.w));
      sum = f4add(sum, ex[j]);
    }
    red[t] = sum;
    __syncthreads();
    for (int off = 128; off > 0; off >>= 1) {
      if (t < off) red[t] = f4add(red[t], red[t + off]);
      __syncthreads();
    }
    const float4 tot = red[0];
    const float inv[4] = {1.f/tot.x, 1.f/tot.y, 1.f/tot.z, 1.f/tot.w};
#pragma unroll
    for (int j = 0; j < 8; ++j) {
      const int m = t + 256 * j;
      A[(size_t)(n0 + 0) * NN + m] = (bf16)(ex[j].x * inv[0]);
      A[(size_t)(n0 + 1) * NN + m] = (bf16)(ex[j].y * inv[1]);
      A[(size_t)(n0 + 2) * NN + m] = (bf16)(ex[j].z * inv[2]);
      A[(size_t)(n0 + 3) * NN + m] = (bf16)(ex[j].w * inv[3]);
    }
  } else if (blk < 2560) {
    // ---- build_xrt: XrT[b*64+i][m] = bf16(x[b][m][i]) ----
    bf16* tile = (bf16*)smem;  // [64][68]
    const int q0 = blk - 512;
    const int b = q0 >> 5;
    const int m0 = (q0 & 31) * 64;
#pragma unroll
    for (int j = 0; j < 16; ++j) {
      const int q = t + 256 * j;
      const int m = q >> 6, i = q & 63;
      tile[m * 68 + i] = (bf16)x[((size_t)b * NN + m0 + m) * CC + i];
    }
    __syncthreads();
#pragma unroll
    for (int j = 0; j < 16; ++j) {
      const int q = t + 256 * j;
      const int i = q >> 6, m = q & 63;
      XrT[((size_t)b * CC + i) * NN + m0 + m] = tile[m * 68 + i];
    }
  } else {
    // ---- prep_wpt: WpT[r][o][d] bf16, e = r*64+o ----
    const int e = (blk - 2560) * 256 + t;  // 0..12287
    const int r = e >> 6, o = e & 63;
    const size_t src = (size_t)(r >> 6) * 4096 + (size_t)(r & 63) * 64 + o;
#pragma unroll
    for (int d = 0; d < DD; ++d)
      WpT[(size_t)e * DD + d] = (bf16)Wp[(size_t)d * 12288 + src];
  }
}

// ---------------- generic bf16 transpose (fallback path only) --------------
__global__ __launch_bounds__(256) void k_transpose(const bf16* __restrict__ in,
                                                   bf16* __restrict__ out,
                                                   int R, int C) {
  __shared__ bf16 tile[64 * 68];
  const int bx = blockIdx.x, by = blockIdx.y;
  const int t = threadIdx.x;
  const int r0 = by * 64, c0 = bx * 64;
#pragma unroll
  for (int j = 0; j < 16; ++j) {
    const int q = t + 256 * j;
    const int r = q >> 6, c = q & 63;
    tile[r * 68 + c] = in[(size_t)(r0 + r) * C + c0 + c];
  }
  __syncthreads();
#pragma unroll
  for (int j = 0; j < 16; ++j) {
    const int q = t + 256 * j;
    const int rr = q >> 6, cc = q & 63;
    out[(size_t)(c0 + rr) * R + r0 + cc] = tile[cc * 68 + rr];
  }
}

// ---------------- GEMM (B^T form): C[m][n] = sum_k L[m][k]*R[n][k] ---------
// FROZEN from R10 (measured: 47.5 us each, FETCH 34 MB, 2D XCD tiling).
// EPI: 0=plain, 1=plain + transposed copy CT[c][m] via LDS, 2 = 2*acc - Xext.
template <int EPI>
__global__ __launch_bounds__(256) void k_gemm_bt(const bf16* __restrict__ L,
                                                 const bf16* __restrict__ R,
                                                 bf16* __restrict__ C,
                                                 int M, int Nc, int K,
                                                 const float* __restrict__ Xext,
                                                 bf16* __restrict__ CT) {
  __shared__ uint4 lds[4096];  // 2 bufs x (1024 L + 1024 R) 16B units = 64 KB
  const int t = threadIdx.x;
  const int lane = t & 63, w = t >> 6;
  const int wm = w & 1, wn = w >> 1;
  const int h = lane >> 4;

  const int nwg = gridDim.x * gridDim.y;
  const int bid = blockIdx.y * gridDim.x + blockIdx.x;
  int bx, by;
  if (gridDim.x == 32 && gridDim.y == 16) {
    const int xcd = bid & 7, j = bid >> 3;          // j = 0..63
    bx = (xcd & 3) * 8 + (j & 7);
    by = (xcd >> 2) * 8 + (j >> 3);
  } else {
    const int cpx = nwg >> 3;
    const int swz = (bid & 7) * cpx + (bid >> 3);
    bx = swz % gridDim.x;
    by = swz / gridDim.x;
  }

  const int m0 = by * 128, n0 = bx * 128;

  f32x4 acc[4][4];
  const f32x4 zz = {0.f, 0.f, 0.f, 0.f};
#pragma unroll
  for (int mt = 0; mt < 4; ++mt)
#pragma unroll
    for (int nt = 0; nt < 4; ++nt) acc[mt][nt] = zz;

  auto stage = [&](int buf, int kt) {
    uint4* base = lds + buf * 2048;
#pragma unroll
    for (int c = 0; c < 4; ++c) {
      const int q = t + 256 * c;
      const int row = q >> 3, col4 = q & 7;
      const int scol = col4 ^ (row & 7);
      const bf16* srcL = L + (size_t)(m0 + row) * K + kt + (scol << 3);
      const bf16* srcR = R + (size_t)(n0 + row) * K + kt + (scol << 3);
      __builtin_amdgcn_global_load_lds(srcL, &base[q & ~63], 16, 0, 0);
      __builtin_amdgcn_global_load_lds(srcR, &base[1024 + (q & ~63)], 16, 0, 0);
    }
  };

  auto compute = [&](int buf) {
    const bf16x8* Lsv = (const bf16x8*)(lds + buf * 2048);
    const bf16x8* Rsv = (const bf16x8*)(lds + buf * 2048 + 1024);
#pragma unroll
    for (int kk = 0; kk < 2; ++kk) {
      bf16x8 af[4], bfr[4];
#pragma unroll
      for (int mt = 0; mt < 4; ++mt) {
        const int row = wm * 64 + mt * 16 + (lane & 15);
        af[mt] = Lsv[(row << 3) | ((kk * 4 + h) ^ (row & 7))];
      }
#pragma unroll
      for (int nt = 0; nt < 4; ++nt) {
        const int row = wn * 64 + nt * 16 + (lane & 15);
        bfr[nt] = Rsv[(row << 3) | ((kk * 4 + h) ^ (row & 7))];
      }
#pragma unroll
      for (int mt = 0; mt < 4; ++mt)
#pragma unroll
        for (int nt = 0; nt < 4; ++nt)
          acc[mt][nt] = __builtin_amdgcn_mfma_f32_16x16x32_bf16(
              af[mt], bfr[nt], acc[mt][nt], 0, 0, 0);
    }
  };

  const int NT = K >> 6;
  stage(0, 0);
  int cur = 0;
  for (int ts = 0; ts < NT - 1; ++ts) {
    stage(cur ^ 1, (ts + 1) << 6);
    asm volatile("s_waitcnt vmcnt(8)" ::: "memory");
    __builtin_amdgcn_s_barrier();
    __builtin_amdgcn_sched_barrier(0);
    compute(cur);
    __builtin_amdgcn_s_barrier();
    __builtin_amdgcn_sched_barrier(0);
    cur ^= 1;
  }
  asm volatile("s_waitcnt vmcnt(0)" ::: "memory");
  __builtin_amdgcn_s_barrier();
  __builtin_amdgcn_sched_barrier(0);
  compute(cur);

  // straight C-write: C/D layout col = lane&15, row = 4*(lane>>4)+r
#pragma unroll
  for (int mt = 0; mt < 4; ++mt)
#pragma unroll
    for (int nt = 0; nt < 4; ++nt)
#pragma unroll
      for (int r = 0; r < 4; ++r) {
        const int rg = m0 + wm * 64 + mt * 16 + 4 * h + r;
        const int cg = n0 + wn * 64 + nt * 16 + (lane & 15);
        float v = acc[mt][nt][r];
        if (EPI == 2) {
          const int b = cg >> 6, i = cg & 63;
          v = 2.0f * v - Xext[(((size_t)b * NN + rg) * CC) + i];
        }
        C[(size_t)rg * Nc + cg] = (bf16)v;
      }

  if (EPI == 1) {
    // fused transpose: CT[n0+cloc][m0+rloc] = acc, via padded LDS tile
    __syncthreads();                    // all waves done with K-loop LDS
    bf16* T = (bf16*)lds;               // [128][136] bf16 = 34 KB
#pragma unroll
    for (int mt = 0; mt < 4; ++mt)
#pragma unroll
      for (int nt = 0; nt < 4; ++nt)
#pragma unroll
        for (int r = 0; r < 4; ++r) {
          const int rloc = wm * 64 + mt * 16 + 4 * h + r;
          const int cloc = wn * 64 + nt * 16 + (lane & 15);
          T[cloc * 136 + rloc] = (bf16)acc[mt][nt][r];
        }
    __syncthreads();
    const int cloc = t >> 1, half = t & 1;
#pragma unroll
    for (int jj = 0; jj < 8; ++jj) {
      const bf16x8 v = *(const bf16x8*)(T + cloc * 136 + half * 64 + jj * 8);
      *(bf16x8*)(CT + (size_t)(n0 + cloc) * M + m0 + half * 64 + jj * 8) = v;
    }
  }
}

// ---------------- K5: gen+apply, 24 KB LDS, node1-W reg-stash --------------
// One WpT pass generates BOTH nodes' W (proven amortization); node0's W goes
// to LDS, node1's W is stashed in 6 bf16x8 regs (static-indexed, rule #20),
// dumped to LDS after apply(0). 24 KB LDS + <=128 VGPR -> 16 waves/CU.
__global__ __launch_bounds__(256, 4) void k_node(const float* __restrict__ x,
                                                 const float* __restrict__ E,
                                                 const bf16* __restrict__ WpT,
                                                 const float* __restrict__ bp,
                                                 const bf16* __restrict__ xg1,
                                                 const bf16* __restrict__ xg2,
                                                 float* __restrict__ out) {
  __shared__ alignas(16) bf16 sW[1536 * 8];  // 24 KB, one node's W at a time
  const int t = threadIdx.x;
  const int lane = t & 63, w = t >> 6;
  const int h = lane >> 4, l16 = lane & 15;
  const int n0 = blockIdx.x * 2;
  const int b = w * 16 + l16;

  // T14 prefetch: both nodes' apply operands
  float4  xa[2][4];
  bf16x8  xgr[2][4];
#pragma unroll
  for (int g = 0; g < 2; ++g) {
    const int n = n0 + g;
    const float* xb = x + ((size_t)b * NN + n) * CC;
    xa[g][0] = *(const float4*)(xb + h * 8);
    xa[g][1] = *(const float4*)(xb + h * 8 + 4);
    xa[g][2] = *(const float4*)(xb + 32 + h * 8);
    xa[g][3] = *(const float4*)(xb + 32 + h * 8 + 4);
    const bf16* x1 = xg1 + (size_t)n * BCC + b * CC;
    const bf16* x2 = xg2 + (size_t)n * BCC + b * CC;
    xgr[g][0] = *(const bf16x8*)(x1 + h * 8);
    xgr[g][1] = *(const bf16x8*)(x1 + 32 + h * 8);
    xgr[g][2] = *(const bf16x8*)(x2 + h * 8);
    xgr[g][3] = *(const bf16x8*)(x2 + 32 + h * 8);
  }

  f32x2 en2[DD];
  float en[2][DD];
#pragma unroll
  for (int g = 0; g < 2; ++g)
#pragma unroll
    for (int d = 0; d < DD; ++d) en[g][d] = E[(size_t)(n0 + g) * DD + d];
#pragma unroll
  for (int d = 0; d < DD; ++d) en2[d] = (f32x2){en[0][d], en[1][d]};

  float bias_v[2][4];
#pragma unroll
  for (int g = 0; g < 2; ++g)
#pragma unroll
    for (int nt = 0; nt < 4; ++nt) {
      const int o = nt * 16 + l16;
      float a = 0.0f;
#pragma unroll
      for (int d = 0; d < DD; ++d) a += en[g][d] * bp[d * CC + o];
      bias_v[g][nt] = a;
    }

  // ---- gen: one WpT pass; node0 W -> LDS, node1 W -> reg stash ----
  bf16x8 wst[6];
#pragma unroll
  for (int c = 0; c < 6; ++c) {
    const int idx = t + 256 * c;
    const int o = idx & 63;
    const int u = idx >> 6;
    const bf16* src = WpT + ((size_t)(u * 8) * 64 + o) * DD;
    bf16x8 wv0, wv1;
#pragma unroll
    for (int j = 0; j < 8; ++j) {
      const bf16x8* wr = (const bf16x8*)(src + (size_t)j * 64 * DD);
      bf16x8 w0 = wr[0], w1 = wr[1];
      f32x2 a2 = {0.f, 0.f};
#pragma unroll
      for (int d = 0; d < 8; ++d) {
        const float wf = (float)w0[d];
        a2 += (f32x2){wf, wf} * en2[d];          // v_pk_fma_f32: both nodes
      }
#pragma unroll
      for (int d = 0; d < 8; ++d) {
        const float wf = (float)w1[d];
        a2 += (f32x2){wf, wf} * en2[8 + d];
      }
      wv0[j] = (bf16)a2[0];
      wv1[j] = (bf16)a2[1];
    }
    const int swz = o * 24 + (u & ~7) + ((u & 7) ^ (o & 7));
    *(bf16x8*)(sW + (size_t)swz * 8) = wv0;
    wst[c] = wv1;
  }
  __syncthreads();

  // ---- apply node0 ----
#pragma unroll
  for (int g = 0; g < 2; ++g) {
    f32x4 acc[4];
    const f32x4 zz = {0.f, 0.f, 0.f, 0.f};
#pragma unroll
    for (int nt = 0; nt < 4; ++nt) acc[nt] = zz;
#pragma unroll
    for (int s = 0; s < 6; ++s) {
      bf16x8 af;
      if (s < 2) {
        const float4 u4 = xa[g][s * 2], v4 = xa[g][s * 2 + 1];
        af[0] = (bf16)u4.x; af[1] = (bf16)u4.y; af[2] = (bf16)u4.z; af[3] = (bf16)u4.w;
        af[4] = (bf16)v4.x; af[5] = (bf16)v4.y; af[6] = (bf16)v4.z; af[7] = (bf16)v4.w;
      } else {
        af = xgr[g][s - 2];
      }
      const int u = s * 4 + h;
#pragma unroll
      for (int nt = 0; nt < 4; ++nt) {
        const int o = nt * 16 + l16;
        const bf16x8 bfr = *(const bf16x8*)(
            sW + (size_t)(o * 24 + (u & ~7) + ((u & 7) ^ (o & 7))) * 8);
        acc[nt] = __builtin_amdgcn_mfma_f32_16x16x32_bf16(af, bfr, acc[nt], 0, 0, 0);
      }
    }
#pragma unroll
    for (int nt = 0; nt < 4; ++nt) {
      const int o = nt * 16 + l16;
#pragma unroll
      for (int r = 0; r < 4; ++r) {
        const int br = w * 16 + 4 * h + r;
        out[((size_t)br * NN + (n0 + g)) * CC + o] = acc[nt][r] + bias_v[g][nt];
      }
    }
    if (g == 0) {
      __syncthreads();   // apply(0) LDS reads complete
      // dump node1's stashed W into LDS
#pragma unroll
      for (int c = 0; c < 6; ++c) {
        const int idx = t + 256 * c;
        const int o = idx & 63;
        const int u = idx >> 6;
        const int swz = o * 24 + (u & ~7) + ((u & 7) ^ (o & 7));
        *(bf16x8*)(sW + (size_t)swz * 8) = wst[c];
      }
      __syncthreads();
    }
  }
}

extern "C" void kernel_launch(void* const* d_in, const int* in_sizes, int n_in,
                              void* d_out, int out_size, void* d_ws, size_t ws_size,
                              hipStream_t stream) {
  const float* x  = (const float*)d_in[0];   // [64,2048,64]
  const float* E  = (const float*)d_in[1];   // [2048,16]
  const float* Wp = (const float*)d_in[2];   // [16,3,64,64]
  const float* bp = (const float*)d_in[3];   // [16,64]
  float* out = (float*)d_out;                // [64,2048,64]

  char* ws = (char*)d_ws;
  const size_t MB = (size_t)1 << 20;
  bf16* A    = (bf16*)(ws);
  bf16* XrT  = (bf16*)(ws + 8 * MB);
  bf16* xg1  = (bf16*)(ws + 24 * MB);
  bf16* xg2  = (bf16*)(ws + 40 * MB);
  bf16* WpT  = (bf16*)(ws + 56 * MB);

  k_prep_fused<<<2608, 256, 0, stream>>>(E, A, x, XrT, Wp, WpT);

  if (ws_size >= 80 * MB) {
    bf16* Xg1T = (bf16*)(ws + 60 * MB);  // [4096][2048], 16 MB (60..76)
    // xg1[n][c] = sum_m A[n][m]*XrT[c][m]; also writes Xg1T[c][n] fused
    k_gemm_bt<1><<<dim3(32, 16), 256, 0, stream>>>(A, XrT, xg1, NN, BCC, NN,
                                                   nullptr, Xg1T);
    k_gemm_bt<2><<<dim3(32, 16), 256, 0, stream>>>(A, Xg1T, xg2, NN, BCC, NN,
                                                   x, nullptr);
  } else {
    bf16* Xg1T = XrT;  // fallback: reuse XrT slot, separate transpose kernel
    k_gemm_bt<0><<<dim3(32, 16), 256, 0, stream>>>(A, XrT, xg1, NN, BCC, NN,
                                                   nullptr, nullptr);
    k_transpose<<<dim3(64, 32), 256, 0, stream>>>(xg1, Xg1T, NN, BCC);
    k_gemm_bt<2><<<dim3(32, 16), 256, 0, stream>>>(A, Xg1T, xg2, NN, BCC, NN,
                                                   x, nullptr);
  }
  k_node<<<NN / 2, 256, 0, stream>>>(x, E, WpT, bp, xg1, xg2, out);
}

// Round 12
// 130.812 us; speedup vs baseline: 1.0620x; 1.0620x over previous
//
#include <hip/hip_runtime.h>
#include <hip/hip_bf16.h>
#include <stdint.h>

using bf16   = __bf16;
using bf16x8 = __attribute__((ext_vector_type(8))) __bf16;
using f32x2  = __attribute__((ext_vector_type(2))) float;
using f32x4  = __attribute__((ext_vector_type(4))) float;

#define NN  2048   // nodes
#define DD  16     // embedding dim
#define BB  64     // batch
#define CC  64     // channels (in == out)
#define BCC 4096   // BB*CC
#define GNODE 2    // nodes per k_node block

__device__ inline float4 f4max(float4 a, float4 b) {
  return make_float4(fmaxf(a.x,b.x), fmaxf(a.y,b.y), fmaxf(a.z,b.z), fmaxf(a.w,b.w));
}
__device__ inline float4 f4add(float4 a, float4 b) {
  return make_float4(a.x+b.x, a.y+b.y, a.z+b.z, a.w+b.w);
}

// ---------------- K1 fused prep: softmax | build_xrt | prep_wpt ------------
// blocks 0..511: softmax (4 nodes each); 512..2559: xrt tiles; 2560..2607: wpt
__global__ __launch_bounds__(256) void k_prep_fused(const float* __restrict__ E,
                                                    bf16* __restrict__ A,
                                                    const float* __restrict__ x,
                                                    bf16* __restrict__ XrT,
                                                    const float* __restrict__ Wp,
                                                    bf16* __restrict__ WpT) {
  __shared__ alignas(16) char smem[64 * 68 * 2];  // 8.7 KB union
  const int blk = blockIdx.x;
  const int t = threadIdx.x;

  if (blk < 512) {
    // ---- softmax: A[n] = softmax(relu(E E^T))[n], 4 nodes/block ----
    float4* red = (float4*)smem;
    const int n0 = blk * 4;
    float en[4][DD];
#pragma unroll
    for (int g = 0; g < 4; ++g)
#pragma unroll
      for (int d = 0; d < DD; ++d) en[g][d] = E[(size_t)(n0 + g) * DD + d];

    float4 r[8];
    float4 mx = make_float4(0.f, 0.f, 0.f, 0.f);
#pragma unroll
    for (int j = 0; j < 8; ++j) {
      const int m = t + 256 * j;
      const float4* ep = (const float4*)(E + (size_t)m * DD);
      float4 p0 = ep[0], p1 = ep[1], p2 = ep[2], p3 = ep[3];
      float s[4];
#pragma unroll
      for (int g = 0; g < 4; ++g) {
        s[g] = p0.x*en[g][0] + p0.y*en[g][1] + p0.z*en[g][2] + p0.w*en[g][3]
             + p1.x*en[g][4] + p1.y*en[g][5] + p1.z*en[g][6] + p1.w*en[g][7]
             + p2.x*en[g][8] + p2.y*en[g][9] + p2.z*en[g][10] + p2.w*en[g][11]
             + p3.x*en[g][12]+ p3.y*en[g][13]+ p3.z*en[g][14]+ p3.w*en[g][15];
        s[g] = fmaxf(s[g], 0.0f);
      }
      r[j] = make_float4(s[0], s[1], s[2], s[3]);
      mx = f4max(mx, r[j]);
    }
    red[t] = mx;
    __syncthreads();
    for (int off = 128; off > 0; off >>= 1) {
      if (t < off) red[t] = f4max(red[t], red[t + off]);
      __syncthreads();
    }
    mx = red[0];
    __syncthreads();
    float4 ex[8];
    float4 sum = make_float4(0.f, 0.f, 0.f, 0.f);
#pragma unroll
    for (int j = 0; j < 8; ++j) {
      ex[j] = make_float4(__expf(r[j].x - mx.x), __expf(r[j].y - mx.y),
                          __expf(r[j].z - mx.z), __expf(r[j].w - mx.w));
      sum = f4add(sum, ex[j]);
    }
    red[t] = sum;
    __syncthreads();
    for (int off = 128; off > 0; off >>= 1) {
      if (t < off) red[t] = f4add(red[t], red[t + off]);
      __syncthreads();
    }
    const float4 tot = red[0];
    const float inv[4] = {1.f/tot.x, 1.f/tot.y, 1.f/tot.z, 1.f/tot.w};
#pragma unroll
    for (int j = 0; j < 8; ++j) {
      const int m = t + 256 * j;
      A[(size_t)(n0 + 0) * NN + m] = (bf16)(ex[j].x * inv[0]);
      A[(size_t)(n0 + 1) * NN + m] = (bf16)(ex[j].y * inv[1]);
      A[(size_t)(n0 + 2) * NN + m] = (bf16)(ex[j].z * inv[2]);
      A[(size_t)(n0 + 3) * NN + m] = (bf16)(ex[j].w * inv[3]);
    }
  } else if (blk < 2560) {
    // ---- build_xrt: XrT[b*64+i][m] = bf16(x[b][m][i]) ----
    bf16* tile = (bf16*)smem;  // [64][68]
    const int q0 = blk - 512;
    const int b = q0 >> 5;
    const int m0 = (q0 & 31) * 64;
#pragma unroll
    for (int j = 0; j < 16; ++j) {
      const int q = t + 256 * j;
      const int m = q >> 6, i = q & 63;
      tile[m * 68 + i] = (bf16)x[((size_t)b * NN + m0 + m) * CC + i];
    }
    __syncthreads();
#pragma unroll
    for (int j = 0; j < 16; ++j) {
      const int q = t + 256 * j;
      const int i = q >> 6, m = q & 63;
      XrT[((size_t)b * CC + i) * NN + m0 + m] = tile[m * 68 + i];
    }
  } else {
    // ---- prep_wpt: WpT[r][o][d] bf16, e = r*64+o ----
    const int e = (blk - 2560) * 256 + t;  // 0..12287
    const int r = e >> 6, o = e & 63;
    const size_t src = (size_t)(r >> 6) * 4096 + (size_t)(r & 63) * 64 + o;
#pragma unroll
    for (int d = 0; d < DD; ++d)
      WpT[(size_t)e * DD + d] = (bf16)Wp[(size_t)d * 12288 + src];
  }
}

// ---------------- generic bf16 transpose (fallback path only) --------------
__global__ __launch_bounds__(256) void k_transpose(const bf16* __restrict__ in,
                                                   bf16* __restrict__ out,
                                                   int R, int C) {
  __shared__ bf16 tile[64 * 68];
  const int bx = blockIdx.x, by = blockIdx.y;
  const int t = threadIdx.x;
  const int r0 = by * 64, c0 = bx * 64;
#pragma unroll
  for (int j = 0; j < 16; ++j) {
    const int q = t + 256 * j;
    const int r = q >> 6, c = q & 63;
    tile[r * 68 + c] = in[(size_t)(r0 + r) * C + c0 + c];
  }
  __syncthreads();
#pragma unroll
  for (int j = 0; j < 16; ++j) {
    const int q = t + 256 * j;
    const int rr = q >> 6, cc = q & 63;
    out[(size_t)(c0 + rr) * R + r0 + cc] = tile[cc * 68 + rr];
  }
}

// ---------------- GEMM (B^T form): C[m][n] = sum_k L[m][k]*R[n][k] ---------
// FROZEN from R10 (measured: 47.5 us each, FETCH 34 MB, 2D XCD tiling).
// EPI: 0=plain, 1=plain + transposed copy CT[c][m] via LDS, 2 = 2*acc - Xext.
template <int EPI>
__global__ __launch_bounds__(256) void k_gemm_bt(const bf16* __restrict__ L,
                                                 const bf16* __restrict__ R,
                                                 bf16* __restrict__ C,
                                                 int M, int Nc, int K,
                                                 const float* __restrict__ Xext,
                                                 bf16* __restrict__ CT) {
  __shared__ uint4 lds[4096];  // 2 bufs x (1024 L + 1024 R) 16B units = 64 KB
  const int t = threadIdx.x;
  const int lane = t & 63, w = t >> 6;
  const int wm = w & 1, wn = w >> 1;
  const int h = lane >> 4;

  const int nwg = gridDim.x * gridDim.y;
  const int bid = blockIdx.y * gridDim.x + blockIdx.x;
  int bx, by;
  if (gridDim.x == 32 && gridDim.y == 16) {
    const int xcd = bid & 7, j = bid >> 3;          // j = 0..63
    bx = (xcd & 3) * 8 + (j & 7);
    by = (xcd >> 2) * 8 + (j >> 3);
  } else {
    const int cpx = nwg >> 3;
    const int swz = (bid & 7) * cpx + (bid >> 3);
    bx = swz % gridDim.x;
    by = swz / gridDim.x;
  }

  const int m0 = by * 128, n0 = bx * 128;

  f32x4 acc[4][4];
  const f32x4 zz = {0.f, 0.f, 0.f, 0.f};
#pragma unroll
  for (int mt = 0; mt < 4; ++mt)
#pragma unroll
    for (int nt = 0; nt < 4; ++nt) acc[mt][nt] = zz;

  auto stage = [&](int buf, int kt) {
    uint4* base = lds + buf * 2048;
#pragma unroll
    for (int c = 0; c < 4; ++c) {
      const int q = t + 256 * c;
      const int row = q >> 3, col4 = q & 7;
      const int scol = col4 ^ (row & 7);
      const bf16* srcL = L + (size_t)(m0 + row) * K + kt + (scol << 3);
      const bf16* srcR = R + (size_t)(n0 + row) * K + kt + (scol << 3);
      __builtin_amdgcn_global_load_lds(srcL, &base[q & ~63], 16, 0, 0);
      __builtin_amdgcn_global_load_lds(srcR, &base[1024 + (q & ~63)], 16, 0, 0);
    }
  };

  auto compute = [&](int buf) {
    const bf16x8* Lsv = (const bf16x8*)(lds + buf * 2048);
    const bf16x8* Rsv = (const bf16x8*)(lds + buf * 2048 + 1024);
#pragma unroll
    for (int kk = 0; kk < 2; ++kk) {
      bf16x8 af[4], bfr[4];
#pragma unroll
      for (int mt = 0; mt < 4; ++mt) {
        const int row = wm * 64 + mt * 16 + (lane & 15);
        af[mt] = Lsv[(row << 3) | ((kk * 4 + h) ^ (row & 7))];
      }
#pragma unroll
      for (int nt = 0; nt < 4; ++nt) {
        const int row = wn * 64 + nt * 16 + (lane & 15);
        bfr[nt] = Rsv[(row << 3) | ((kk * 4 + h) ^ (row & 7))];
      }
#pragma unroll
      for (int mt = 0; mt < 4; ++mt)
#pragma unroll
        for (int nt = 0; nt < 4; ++nt)
          acc[mt][nt] = __builtin_amdgcn_mfma_f32_16x16x32_bf16(
              af[mt], bfr[nt], acc[mt][nt], 0, 0, 0);
    }
  };

  const int NT = K >> 6;
  stage(0, 0);
  int cur = 0;
  for (int ts = 0; ts < NT - 1; ++ts) {
    stage(cur ^ 1, (ts + 1) << 6);
    asm volatile("s_waitcnt vmcnt(8)" ::: "memory");
    __builtin_amdgcn_s_barrier();
    __builtin_amdgcn_sched_barrier(0);
    compute(cur);
    __builtin_amdgcn_s_barrier();
    __builtin_amdgcn_sched_barrier(0);
    cur ^= 1;
  }
  asm volatile("s_waitcnt vmcnt(0)" ::: "memory");
  __builtin_amdgcn_s_barrier();
  __builtin_amdgcn_sched_barrier(0);
  compute(cur);

  // straight C-write: C/D layout col = lane&15, row = 4*(lane>>4)+r
#pragma unroll
  for (int mt = 0; mt < 4; ++mt)
#pragma unroll
    for (int nt = 0; nt < 4; ++nt)
#pragma unroll
      for (int r = 0; r < 4; ++r) {
        const int rg = m0 + wm * 64 + mt * 16 + 4 * h + r;
        const int cg = n0 + wn * 64 + nt * 16 + (lane & 15);
        float v = acc[mt][nt][r];
        if (EPI == 2) {
          const int b = cg >> 6, i = cg & 63;
          v = 2.0f * v - Xext[(((size_t)b * NN + rg) * CC) + i];
        }
        C[(size_t)rg * Nc + cg] = (bf16)v;
      }

  if (EPI == 1) {
    // fused transpose: CT[n0+cloc][m0+rloc] = acc, via padded LDS tile
    __syncthreads();                    // all waves done with K-loop LDS
    bf16* T = (bf16*)lds;               // [128][136] bf16 = 34 KB
#pragma unroll
    for (int mt = 0; mt < 4; ++mt)
#pragma unroll
      for (int nt = 0; nt < 4; ++nt)
#pragma unroll
        for (int r = 0; r < 4; ++r) {
          const int rloc = wm * 64 + mt * 16 + 4 * h + r;
          const int cloc = wn * 64 + nt * 16 + (lane & 15);
          T[cloc * 136 + rloc] = (bf16)acc[mt][nt][r];
        }
    __syncthreads();
    const int cloc = t >> 1, half = t & 1;
#pragma unroll
    for (int jj = 0; jj < 8; ++jj) {
      const bf16x8 v = *(const bf16x8*)(T + cloc * 136 + half * 64 + jj * 8);
      *(bf16x8*)(CT + (size_t)(n0 + cloc) * M + m0 + half * 64 + jj * 8) = v;
    }
  }
}

// ---------------- K5: R10-proven fused gen+apply (256t, GNODE=2, pk-fma) ---
__global__ __launch_bounds__(256) void k_node(const float* __restrict__ x,
                                              const float* __restrict__ E,
                                              const bf16* __restrict__ WpT,
                                              const float* __restrict__ bp,
                                              const bf16* __restrict__ xg1,
                                              const bf16* __restrict__ xg2,
                                              float* __restrict__ out) {
  __shared__ alignas(16) bf16 sW[GNODE * 1536 * 8];  // 48 KB
  const int t = threadIdx.x;
  const int lane = t & 63, w = t >> 6;
  const int h = lane >> 4, l16 = lane & 15;
  const int n0 = blockIdx.x * GNODE;
  const int b = w * 16 + l16;

  float4  xa[GNODE][4];
  bf16x8  xgr[GNODE][4];
#pragma unroll
  for (int g = 0; g < GNODE; ++g) {
    const int n = n0 + g;
    const float* xb = x + ((size_t)b * NN + n) * CC;
    xa[g][0] = *(const float4*)(xb + h * 8);
    xa[g][1] = *(const float4*)(xb + h * 8 + 4);
    xa[g][2] = *(const float4*)(xb + 32 + h * 8);
    xa[g][3] = *(const float4*)(xb + 32 + h * 8 + 4);
    const bf16* x1 = xg1 + (size_t)n * BCC + b * CC;
    const bf16* x2 = xg2 + (size_t)n * BCC + b * CC;
    xgr[g][0] = *(const bf16x8*)(x1 + h * 8);
    xgr[g][1] = *(const bf16x8*)(x1 + 32 + h * 8);
    xgr[g][2] = *(const bf16x8*)(x2 + h * 8);
    xgr[g][3] = *(const bf16x8*)(x2 + 32 + h * 8);
  }

  // en packed for dual-node pk-fma gen: en2[d] = (en[node0][d], en[node1][d])
  f32x2 en2[DD];
  float en[GNODE][DD];
#pragma unroll
  for (int g = 0; g < GNODE; ++g)
#pragma unroll
    for (int d = 0; d < DD; ++d) en[g][d] = E[(size_t)(n0 + g) * DD + d];
#pragma unroll
  for (int d = 0; d < DD; ++d) en2[d] = (f32x2){en[0][d], en[1][d]};

  float bias_v[GNODE][4];
#pragma unroll
  for (int g = 0; g < GNODE; ++g)
#pragma unroll
    for (int nt = 0; nt < 4; ++nt) {
      const int o = nt * 16 + l16;
      float a = 0.0f;
#pragma unroll
      for (int d = 0; d < DD; ++d) a += en[g][d] * bp[d * CC + o];
      bias_v[g][nt] = a;
    }

#pragma unroll
  for (int c = 0; c < 6; ++c) {
    const int idx = t + 256 * c;
    const int o = idx & 63;
    const int u = idx >> 6;
    const bf16* src = WpT + ((size_t)(u * 8) * 64 + o) * DD;
    bf16x8 wv[GNODE];
#pragma unroll
    for (int j = 0; j < 8; ++j) {
      const bf16x8* wr = (const bf16x8*)(src + (size_t)j * 64 * DD);
      bf16x8 w0 = wr[0], w1 = wr[1];
      f32x2 a2 = {0.f, 0.f};
#pragma unroll
      for (int d = 0; d < 8; ++d) {
        const float wf = (float)w0[d];
        a2 += (f32x2){wf, wf} * en2[d];          // v_pk_fma_f32: both nodes
      }
#pragma unroll
      for (int d = 0; d < 8; ++d) {
        const float wf = (float)w1[d];
        a2 += (f32x2){wf, wf} * en2[8 + d];
      }
      wv[0][j] = (bf16)a2[0];
      wv[1][j] = (bf16)a2[1];
    }
    const int swz = o * 24 + (u & ~7) + ((u & 7) ^ (o & 7));
#pragma unroll
    for (int g = 0; g < GNODE; ++g)
      *(bf16x8*)(sW + (size_t)(g * 1536 + swz) * 8) = wv[g];
  }
  __syncthreads();

#pragma unroll
  for (int g = 0; g < GNODE; ++g) {
    f32x4 acc[4];
    const f32x4 zz = {0.f, 0.f, 0.f, 0.f};
#pragma unroll
    for (int nt = 0; nt < 4; ++nt) acc[nt] = zz;
#pragma unroll
    for (int s = 0; s < 6; ++s) {
      bf16x8 af;
      if (s < 2) {
        const float4 u4 = xa[g][s * 2], v4 = xa[g][s * 2 + 1];
        af[0] = (bf16)u4.x; af[1] = (bf16)u4.y; af[2] = (bf16)u4.z; af[3] = (bf16)u4.w;
        af[4] = (bf16)v4.x; af[5] = (bf16)v4.y; af[6] = (bf16)v4.z; af[7] = (bf16)v4.w;
      } else {
        af = xgr[g][s - 2];
      }
      const int u = s * 4 + h;
#pragma unroll
      for (int nt = 0; nt < 4; ++nt) {
        const int o = nt * 16 + l16;
        const bf16x8 bfr = *(const bf16x8*)(
            sW + (size_t)(g * 1536 + o * 24 + (u & ~7) + ((u & 7) ^ (o & 7))) * 8);
        acc[nt] = __builtin_amdgcn_mfma_f32_16x16x32_bf16(af, bfr, acc[nt], 0, 0, 0);
      }
    }
#pragma unroll
    for (int nt = 0; nt < 4; ++nt) {
      const int o = nt * 16 + l16;
#pragma unroll
      for (int r = 0; r < 4; ++r) {
        const int br = w * 16 + 4 * h + r;
        out[((size_t)br * NN + (n0 + g)) * CC + o] = acc[nt][r] + bias_v[g][nt];
      }
    }
  }
}

extern "C" void kernel_launch(void* const* d_in, const int* in_sizes, int n_in,
                              void* d_out, int out_size, void* d_ws, size_t ws_size,
                              hipStream_t stream) {
  const float* x  = (const float*)d_in[0];   // [64,2048,64]
  const float* E  = (const float*)d_in[1];   // [2048,16]
  const float* Wp = (const float*)d_in[2];   // [16,3,64,64]
  const float* bp = (const float*)d_in[3];   // [16,64]
  float* out = (float*)d_out;                // [64,2048,64]

  char* ws = (char*)d_ws;
  const size_t MB = (size_t)1 << 20;
  bf16* A    = (bf16*)(ws);
  bf16* XrT  = (bf16*)(ws + 8 * MB);
  bf16* xg1  = (bf16*)(ws + 24 * MB);
  bf16* xg2  = (bf16*)(ws + 40 * MB);
  bf16* WpT  = (bf16*)(ws + 56 * MB);

  k_prep_fused<<<2608, 256, 0, stream>>>(E, A, x, XrT, Wp, WpT);

  if (ws_size >= 80 * MB) {
    bf16* Xg1T = (bf16*)(ws + 60 * MB);  // [4096][2048], 16 MB (60..76)
    // xg1[n][c] = sum_m A[n][m]*XrT[c][m]; also writes Xg1T[c][n] fused
    k_gemm_bt<1><<<dim3(32, 16), 256, 0, stream>>>(A, XrT, xg1, NN, BCC, NN,
                                                   nullptr, Xg1T);
    k_gemm_bt<2><<<dim3(32, 16), 256, 0, stream>>>(A, Xg1T, xg2, NN, BCC, NN,
                                                   x, nullptr);
  } else {
    bf16* Xg1T = XrT;  // fallback: reuse XrT slot, separate transpose kernel
    k_gemm_bt<0><<<dim3(32, 16), 256, 0, stream>>>(A, XrT, xg1, NN, BCC, NN,
                                                   nullptr, nullptr);
    k_transpose<<<dim3(64, 32), 256, 0, stream>>>(xg1, Xg1T, NN, BCC);
    k_gemm_bt<2><<<dim3(32, 16), 256, 0, stream>>>(A, Xg1T, xg2, NN, BCC, NN,
                                                   x, nullptr);
  }
  k_node<<<NN / GNODE, 256, 0, stream>>>(x, E, WpT, bp, xg1, xg2, out);
}

// Round 13
// 128.874 us; speedup vs baseline: 1.0780x; 1.0150x over previous
//
#include <hip/hip_runtime.h>
#include <hip/hip_bf16.h>
#include <stdint.h>

using bf16   = __bf16;
using bf16x8 = __attribute__((ext_vector_type(8))) __bf16;
using f32x2  = __attribute__((ext_vector_type(2))) float;
using f32x4  = __attribute__((ext_vector_type(4))) float;

#define NN  2048   // nodes
#define DD  16     // embedding dim
#define BB  64     // batch
#define CC  64     // channels (in == out)
#define BCC 4096   // BB*CC
#define GNODE 2    // nodes per k_node block

__device__ inline float4 f4max(float4 a, float4 b) {
  return make_float4(fmaxf(a.x,b.x), fmaxf(a.y,b.y), fmaxf(a.z,b.z), fmaxf(a.w,b.w));
}
__device__ inline float4 f4add(float4 a, float4 b) {
  return make_float4(a.x+b.x, a.y+b.y, a.z+b.z, a.w+b.w);
}

// ---------------- K1 fused prep: softmax | build_xrt | prep_wpt ------------
// blocks 0..511: softmax (4 nodes each); 512..2559: xrt tiles; 2560..2607: wpt
__global__ __launch_bounds__(256) void k_prep_fused(const float* __restrict__ E,
                                                    bf16* __restrict__ A,
                                                    const float* __restrict__ x,
                                                    bf16* __restrict__ XrT,
                                                    const float* __restrict__ Wp,
                                                    bf16* __restrict__ WpT) {
  __shared__ alignas(16) char smem[64 * 68 * 2];  // 8.7 KB union
  const int blk = blockIdx.x;
  const int t = threadIdx.x;

  if (blk < 512) {
    // ---- softmax: A[n] = softmax(relu(E E^T))[n], 4 nodes/block ----
    float4* red = (float4*)smem;
    const int n0 = blk * 4;
    float en[4][DD];
#pragma unroll
    for (int g = 0; g < 4; ++g)
#pragma unroll
      for (int d = 0; d < DD; ++d) en[g][d] = E[(size_t)(n0 + g) * DD + d];

    float4 r[8];
    float4 mx = make_float4(0.f, 0.f, 0.f, 0.f);
#pragma unroll
    for (int j = 0; j < 8; ++j) {
      const int m = t + 256 * j;
      const float4* ep = (const float4*)(E + (size_t)m * DD);
      float4 p0 = ep[0], p1 = ep[1], p2 = ep[2], p3 = ep[3];
      float s[4];
#pragma unroll
      for (int g = 0; g < 4; ++g) {
        s[g] = p0.x*en[g][0] + p0.y*en[g][1] + p0.z*en[g][2] + p0.w*en[g][3]
             + p1.x*en[g][4] + p1.y*en[g][5] + p1.z*en[g][6] + p1.w*en[g][7]
             + p2.x*en[g][8] + p2.y*en[g][9] + p2.z*en[g][10] + p2.w*en[g][11]
             + p3.x*en[g][12]+ p3.y*en[g][13]+ p3.z*en[g][14]+ p3.w*en[g][15];
        s[g] = fmaxf(s[g], 0.0f);
      }
      r[j] = make_float4(s[0], s[1], s[2], s[3]);
      mx = f4max(mx, r[j]);
    }
    red[t] = mx;
    __syncthreads();
    for (int off = 128; off > 0; off >>= 1) {
      if (t < off) red[t] = f4max(red[t], red[t + off]);
      __syncthreads();
    }
    mx = red[0];
    __syncthreads();
    float4 ex[8];
    float4 sum = make_float4(0.f, 0.f, 0.f, 0.f);
#pragma unroll
    for (int j = 0; j < 8; ++j) {
      ex[j] = make_float4(__expf(r[j].x - mx.x), __expf(r[j].y - mx.y),
                          __expf(r[j].z - mx.z), __expf(r[j].w - mx.w));
      sum = f4add(sum, ex[j]);
    }
    red[t] = sum;
    __syncthreads();
    for (int off = 128; off > 0; off >>= 1) {
      if (t < off) red[t] = f4add(red[t], red[t + off]);
      __syncthreads();
    }
    const float4 tot = red[0];
    const float inv[4] = {1.f/tot.x, 1.f/tot.y, 1.f/tot.z, 1.f/tot.w};
#pragma unroll
    for (int j = 0; j < 8; ++j) {
      const int m = t + 256 * j;
      A[(size_t)(n0 + 0) * NN + m] = (bf16)(ex[j].x * inv[0]);
      A[(size_t)(n0 + 1) * NN + m] = (bf16)(ex[j].y * inv[1]);
      A[(size_t)(n0 + 2) * NN + m] = (bf16)(ex[j].z * inv[2]);
      A[(size_t)(n0 + 3) * NN + m] = (bf16)(ex[j].w * inv[3]);
    }
  } else if (blk < 2560) {
    // ---- build_xrt: XrT[b*64+i][m] = bf16(x[b][m][i]) ----
    bf16* tile = (bf16*)smem;  // [64][68]
    const int q0 = blk - 512;
    const int b = q0 >> 5;
    const int m0 = (q0 & 31) * 64;
#pragma unroll
    for (int j = 0; j < 16; ++j) {
      const int q = t + 256 * j;
      const int m = q >> 6, i = q & 63;
      tile[m * 68 + i] = (bf16)x[((size_t)b * NN + m0 + m) * CC + i];
    }
    __syncthreads();
#pragma unroll
    for (int j = 0; j < 16; ++j) {
      const int q = t + 256 * j;
      const int i = q >> 6, m = q & 63;
      XrT[((size_t)b * CC + i) * NN + m0 + m] = tile[m * 68 + i];
    }
  } else {
    // ---- prep_wpt: WpT[r][o][d] bf16, e = r*64+o ----
    const int e = (blk - 2560) * 256 + t;  // 0..12287
    const int r = e >> 6, o = e & 63;
    const size_t src = (size_t)(r >> 6) * 4096 + (size_t)(r & 63) * 64 + o;
#pragma unroll
    for (int d = 0; d < DD; ++d)
      WpT[(size_t)e * DD + d] = (bf16)Wp[(size_t)d * 12288 + src];
  }
}

// ---------------- generic bf16 transpose (fallback path only) --------------
__global__ __launch_bounds__(256) void k_transpose(const bf16* __restrict__ in,
                                                   bf16* __restrict__ out,
                                                   int R, int C) {
  __shared__ bf16 tile[64 * 68];
  const int bx = blockIdx.x, by = blockIdx.y;
  const int t = threadIdx.x;
  const int r0 = by * 64, c0 = bx * 64;
#pragma unroll
  for (int j = 0; j < 16; ++j) {
    const int q = t + 256 * j;
    const int r = q >> 6, c = q & 63;
    tile[r * 68 + c] = in[(size_t)(r0 + r) * C + c0 + c];
  }
  __syncthreads();
#pragma unroll
  for (int j = 0; j < 16; ++j) {
    const int q = t + 256 * j;
    const int rr = q >> 6, cc = q & 63;
    out[(size_t)(c0 + rr) * R + r0 + cc] = tile[cc * 68 + rr];
  }
}

// ---------------- GEMM (B^T form): C[m][n] = sum_k L[m][k]*R[n][k] ---------
// R13: 512 threads / 8 waves (2x4), same 128x128x64 dbuf tile -> 16 waves/CU
// (2 blocks/CU x 8). Per-wave: 64x32 out, 16 MFMA/K-step, 4 staging ops,
// counted vmcnt(4). T1 2D-XCD map + T3-min 2-phase unchanged from R10.
// EPI: 0=plain, 1=plain + transposed copy CT[c][m] via LDS, 2 = 2*acc - Xext.
template <int EPI>
__global__ __launch_bounds__(512) void k_gemm_bt(const bf16* __restrict__ L,
                                                 const bf16* __restrict__ R,
                                                 bf16* __restrict__ C,
                                                 int M, int Nc, int K,
                                                 const float* __restrict__ Xext,
                                                 bf16* __restrict__ CT) {
  __shared__ uint4 lds[4096];  // 2 bufs x (1024 L + 1024 R) 16B units = 64 KB
  const int t = threadIdx.x;
  const int lane = t & 63, w = t >> 6;   // w = 0..7
  const int wm = w & 1, wn = w >> 1;     // 2 x 4 wave grid
  const int h = lane >> 4;

  const int nwg = gridDim.x * gridDim.y;
  const int bid = blockIdx.y * gridDim.x + blockIdx.x;
  int bx, by;
  if (gridDim.x == 32 && gridDim.y == 16) {
    const int xcd = bid & 7, j = bid >> 3;          // j = 0..63
    bx = (xcd & 3) * 8 + (j & 7);
    by = (xcd >> 2) * 8 + (j >> 3);
  } else {
    const int cpx = nwg >> 3;
    const int swz = (bid & 7) * cpx + (bid >> 3);
    bx = swz % gridDim.x;
    by = swz / gridDim.x;
  }

  const int m0 = by * 128, n0 = bx * 128;

  f32x4 acc[4][2];
  const f32x4 zz = {0.f, 0.f, 0.f, 0.f};
#pragma unroll
  for (int mt = 0; mt < 4; ++mt)
#pragma unroll
    for (int nt = 0; nt < 2; ++nt) acc[mt][nt] = zz;

  auto stage = [&](int buf, int kt) {
    uint4* base = lds + buf * 2048;
#pragma unroll
    for (int c = 0; c < 2; ++c) {
      const int q = t + 512 * c;          // 0..1023
      const int row = q >> 3, col4 = q & 7;
      const int scol = col4 ^ (row & 7);
      const bf16* srcL = L + (size_t)(m0 + row) * K + kt + (scol << 3);
      const bf16* srcR = R + (size_t)(n0 + row) * K + kt + (scol << 3);
      __builtin_amdgcn_global_load_lds(srcL, &base[q & ~63], 16, 0, 0);
      __builtin_amdgcn_global_load_lds(srcR, &base[1024 + (q & ~63)], 16, 0, 0);
    }
  };

  auto compute = [&](int buf) {
    const bf16x8* Lsv = (const bf16x8*)(lds + buf * 2048);
    const bf16x8* Rsv = (const bf16x8*)(lds + buf * 2048 + 1024);
#pragma unroll
    for (int kk = 0; kk < 2; ++kk) {
      bf16x8 af[4], bfr[2];
#pragma unroll
      for (int mt = 0; mt < 4; ++mt) {
        const int row = wm * 64 + mt * 16 + (lane & 15);
        af[mt] = Lsv[(row << 3) | ((kk * 4 + h) ^ (row & 7))];
      }
#pragma unroll
      for (int nt = 0; nt < 2; ++nt) {
        const int row = wn * 32 + nt * 16 + (lane & 15);
        bfr[nt] = Rsv[(row << 3) | ((kk * 4 + h) ^ (row & 7))];
      }
#pragma unroll
      for (int mt = 0; mt < 4; ++mt)
#pragma unroll
        for (int nt = 0; nt < 2; ++nt)
          acc[mt][nt] = __builtin_amdgcn_mfma_f32_16x16x32_bf16(
              af[mt], bfr[nt], acc[mt][nt], 0, 0, 0);
    }
  };

  const int NT = K >> 6;
  stage(0, 0);
  int cur = 0;
  for (int ts = 0; ts < NT - 1; ++ts) {
    stage(cur ^ 1, (ts + 1) << 6);               // 4 vm ops issued
    asm volatile("s_waitcnt vmcnt(4)" ::: "memory");  // prev tile's 4 landed
    __builtin_amdgcn_s_barrier();
    __builtin_amdgcn_sched_barrier(0);
    compute(cur);
    __builtin_amdgcn_s_barrier();
    __builtin_amdgcn_sched_barrier(0);
    cur ^= 1;
  }
  asm volatile("s_waitcnt vmcnt(0)" ::: "memory");
  __builtin_amdgcn_s_barrier();
  __builtin_amdgcn_sched_barrier(0);
  compute(cur);

  // straight C-write: C/D layout col = lane&15, row = 4*(lane>>4)+r
#pragma unroll
  for (int mt = 0; mt < 4; ++mt)
#pragma unroll
    for (int nt = 0; nt < 2; ++nt)
#pragma unroll
      for (int r = 0; r < 4; ++r) {
        const int rg = m0 + wm * 64 + mt * 16 + 4 * h + r;
        const int cg = n0 + wn * 32 + nt * 16 + (lane & 15);
        float v = acc[mt][nt][r];
        if (EPI == 2) {
          const int b = cg >> 6, i = cg & 63;
          v = 2.0f * v - Xext[(((size_t)b * NN + rg) * CC) + i];
        }
        C[(size_t)rg * Nc + cg] = (bf16)v;
      }

  if (EPI == 1) {
    // fused transpose: CT[n0+cloc][m0+rloc] = acc, via padded LDS tile
    __syncthreads();                    // all waves done with K-loop LDS
    bf16* T = (bf16*)lds;               // [128][136] bf16 = 34 KB
#pragma unroll
    for (int mt = 0; mt < 4; ++mt)
#pragma unroll
      for (int nt = 0; nt < 2; ++nt)
#pragma unroll
        for (int r = 0; r < 4; ++r) {
          const int rloc = wm * 64 + mt * 16 + 4 * h + r;
          const int cloc = wn * 32 + nt * 16 + (lane & 15);
          T[cloc * 136 + rloc] = (bf16)acc[mt][nt][r];
        }
    __syncthreads();
    const int cloc = t >> 2, quarter = t & 3;
#pragma unroll
    for (int jj = 0; jj < 4; ++jj) {
      const bf16x8 v = *(const bf16x8*)(T + cloc * 136 + quarter * 32 + jj * 8);
      *(bf16x8*)(CT + (size_t)(n0 + cloc) * M + m0 + quarter * 32 + jj * 8) = v;
    }
  }
}

// ---------------- K5: R10/R12-proven fused gen+apply (256t, GNODE=2) -------
__global__ __launch_bounds__(256) void k_node(const float* __restrict__ x,
                                              const float* __restrict__ E,
                                              const bf16* __restrict__ WpT,
                                              const float* __restrict__ bp,
                                              const bf16* __restrict__ xg1,
                                              const bf16* __restrict__ xg2,
                                              float* __restrict__ out) {
  __shared__ alignas(16) bf16 sW[GNODE * 1536 * 8];  // 48 KB
  const int t = threadIdx.x;
  const int lane = t & 63, w = t >> 6;
  const int h = lane >> 4, l16 = lane & 15;
  const int n0 = blockIdx.x * GNODE;
  const int b = w * 16 + l16;

  float4  xa[GNODE][4];
  bf16x8  xgr[GNODE][4];
#pragma unroll
  for (int g = 0; g < GNODE; ++g) {
    const int n = n0 + g;
    const float* xb = x + ((size_t)b * NN + n) * CC;
    xa[g][0] = *(const float4*)(xb + h * 8);
    xa[g][1] = *(const float4*)(xb + h * 8 + 4);
    xa[g][2] = *(const float4*)(xb + 32 + h * 8);
    xa[g][3] = *(const float4*)(xb + 32 + h * 8 + 4);
    const bf16* x1 = xg1 + (size_t)n * BCC + b * CC;
    const bf16* x2 = xg2 + (size_t)n * BCC + b * CC;
    xgr[g][0] = *(const bf16x8*)(x1 + h * 8);
    xgr[g][1] = *(const bf16x8*)(x1 + 32 + h * 8);
    xgr[g][2] = *(const bf16x8*)(x2 + h * 8);
    xgr[g][3] = *(const bf16x8*)(x2 + 32 + h * 8);
  }

  // en packed for dual-node pk-fma gen: en2[d] = (en[node0][d], en[node1][d])
  f32x2 en2[DD];
  float en[GNODE][DD];
#pragma unroll
  for (int g = 0; g < GNODE; ++g)
#pragma unroll
    for (int d = 0; d < DD; ++d) en[g][d] = E[(size_t)(n0 + g) * DD + d];
#pragma unroll
  for (int d = 0; d < DD; ++d) en2[d] = (f32x2){en[0][d], en[1][d]};

  float bias_v[GNODE][4];
#pragma unroll
  for (int g = 0; g < GNODE; ++g)
#pragma unroll
    for (int nt = 0; nt < 4; ++nt) {
      const int o = nt * 16 + l16;
      float a = 0.0f;
#pragma unroll
      for (int d = 0; d < DD; ++d) a += en[g][d] * bp[d * CC + o];
      bias_v[g][nt] = a;
    }

#pragma unroll
  for (int c = 0; c < 6; ++c) {
    const int idx = t + 256 * c;
    const int o = idx & 63;
    const int u = idx >> 6;
    const bf16* src = WpT + ((size_t)(u * 8) * 64 + o) * DD;
    bf16x8 wv[GNODE];
#pragma unroll
    for (int j = 0; j < 8; ++j) {
      const bf16x8* wr = (const bf16x8*)(src + (size_t)j * 64 * DD);
      bf16x8 w0 = wr[0], w1 = wr[1];
      f32x2 a2 = {0.f, 0.f};
#pragma unroll
      for (int d = 0; d < 8; ++d) {
        const float wf = (float)w0[d];
        a2 += (f32x2){wf, wf} * en2[d];          // v_pk_fma_f32: both nodes
      }
#pragma unroll
      for (int d = 0; d < 8; ++d) {
        const float wf = (float)w1[d];
        a2 += (f32x2){wf, wf} * en2[8 + d];
      }
      wv[0][j] = (bf16)a2[0];
      wv[1][j] = (bf16)a2[1];
    }
    const int swz = o * 24 + (u & ~7) + ((u & 7) ^ (o & 7));
#pragma unroll
    for (int g = 0; g < GNODE; ++g)
      *(bf16x8*)(sW + (size_t)(g * 1536 + swz) * 8) = wv[g];
  }
  __syncthreads();

#pragma unroll
  for (int g = 0; g < GNODE; ++g) {
    f32x4 acc[4];
    const f32x4 zz = {0.f, 0.f, 0.f, 0.f};
#pragma unroll
    for (int nt = 0; nt < 4; ++nt) acc[nt] = zz;
#pragma unroll
    for (int s = 0; s < 6; ++s) {
      bf16x8 af;
      if (s < 2) {
        const float4 u4 = xa[g][s * 2], v4 = xa[g][s * 2 + 1];
        af[0] = (bf16)u4.x; af[1] = (bf16)u4.y; af[2] = (bf16)u4.z; af[3] = (bf16)u4.w;
        af[4] = (bf16)v4.x; af[5] = (bf16)v4.y; af[6] = (bf16)v4.z; af[7] = (bf16)v4.w;
      } else {
        af = xgr[g][s - 2];
      }
      const int u = s * 4 + h;
#pragma unroll
      for (int nt = 0; nt < 4; ++nt) {
        const int o = nt * 16 + l16;
        const bf16x8 bfr = *(const bf16x8*)(
            sW + (size_t)(g * 1536 + o * 24 + (u & ~7) + ((u & 7) ^ (o & 7))) * 8);
        acc[nt] = __builtin_amdgcn_mfma_f32_16x16x32_bf16(af, bfr, acc[nt], 0, 0, 0);
      }
    }
#pragma unroll
    for (int nt = 0; nt < 4; ++nt) {
      const int o = nt * 16 + l16;
#pragma unroll
      for (int r = 0; r < 4; ++r) {
        const int br = w * 16 + 4 * h + r;
        out[((size_t)br * NN + (n0 + g)) * CC + o] = acc[nt][r] + bias_v[g][nt];
      }
    }
  }
}

extern "C" void kernel_launch(void* const* d_in, const int* in_sizes, int n_in,
                              void* d_out, int out_size, void* d_ws, size_t ws_size,
                              hipStream_t stream) {
  const float* x  = (const float*)d_in[0];   // [64,2048,64]
  const float* E  = (const float*)d_in[1];   // [2048,16]
  const float* Wp = (const float*)d_in[2];   // [16,3,64,64]
  const float* bp = (const float*)d_in[3];   // [16,64]
  float* out = (float*)d_out;                // [64,2048,64]

  char* ws = (char*)d_ws;
  const size_t MB = (size_t)1 << 20;
  bf16* A    = (bf16*)(ws);
  bf16* XrT  = (bf16*)(ws + 8 * MB);
  bf16* xg1  = (bf16*)(ws + 24 * MB);
  bf16* xg2  = (bf16*)(ws + 40 * MB);
  bf16* WpT  = (bf16*)(ws + 56 * MB);

  k_prep_fused<<<2608, 256, 0, stream>>>(E, A, x, XrT, Wp, WpT);

  if (ws_size >= 80 * MB) {
    bf16* Xg1T = (bf16*)(ws + 60 * MB);  // [4096][2048], 16 MB (60..76)
    // xg1[n][c] = sum_m A[n][m]*XrT[c][m]; also writes Xg1T[c][n] fused
    k_gemm_bt<1><<<dim3(32, 16), 512, 0, stream>>>(A, XrT, xg1, NN, BCC, NN,
                                                   nullptr, Xg1T);
    k_gemm_bt<2><<<dim3(32, 16), 512, 0, stream>>>(A, Xg1T, xg2, NN, BCC, NN,
                                                   x, nullptr);
  } else {
    bf16* Xg1T = XrT;  // fallback: reuse XrT slot, separate transpose kernel
    k_gemm_bt<0><<<dim3(32, 16), 512, 0, stream>>>(A, XrT, xg1, NN, BCC, NN,
                                                   nullptr, nullptr);
    k_transpose<<<dim3(64, 32), 256, 0, stream>>>(xg1, Xg1T, NN, BCC);
    k_gemm_bt<2><<<dim3(32, 16), 512, 0, stream>>>(A, Xg1T, xg2, NN, BCC, NN,
                                                   x, nullptr);
  }
  k_node<<<NN / GNODE, 256, 0, stream>>>(x, E, WpT, bp, xg1, xg2, out);
}